// Round 7
// baseline (336.996 us; speedup 1.0000x reference)
//
#include <hip/hip_runtime.h>

// CombinedLoss: 0.7*MSE + 0.3*mean_b softDTW_gamma.  B=64, T=1024, C=8, fp32.
// R14 = R13 + bank-conflict-free swizzled column layout.
// R13 win (395->268us) exposed 16-way LDS conflicts on the per-lane D loads
// (SQ_LDS_BANK_CONFLICT 192K -> 8.5M): lane l reads col j=J-l, stride -32B
// -> lanes {l,l+4,...} share a 4-bank cluster.  Fix: store col j's float4
// pair at idx4(j) = 2j + ((j>>2)&7) (padded array) -> bank rotation makes
// collisions only at dj=32 (2-way = free per m136).  Also tree-add (1+ea)+eb
// in the softmin chain.  Everything else identical to R13: fused R(u)||D(u+1)
// windows, 256 blocks x 256 thr, 1 wave/SIMD, free-running waves, LDS
// progress flags intra-block, self-validating 8B atomics cross-block.
// ws: [0,256) mse | [256,320) sdtw | u64 rings @ float-offset 320 (~1.6 MB).

constexpr int TT = 1024;
constexpr float ALPHA_ = 0.7f;
constexpr float FINF = 1000000000.0f;
constexpr int RING = 1088;

__device__ __forceinline__ float shflup1(float old0, float v) {
    return __int_as_float(__builtin_amdgcn_update_dpp(
        __float_as_int(old0), __float_as_int(v), 0x138, 0xf, 0xf, false));
}
__device__ __forceinline__ float rotdn1(float v) {
    return __int_as_float(__builtin_amdgcn_update_dpp(
        0, __float_as_int(v), 0x130, 0xf, 0xf, false));
}

__global__ __launch_bounds__(256) void sdtw_band_kernel(
    const float* __restrict__ pred, const float* __restrict__ target,
    float* __restrict__ ws)
{
    // col j: A-half at idx4(j)=2j+((j>>2)&7), B-half at idx4(j)+1
    __shared__ float4 s_c4[2056];
    __shared__ float  s_y2[TT];
    __shared__ float  s_row[4][1088];    // per-wave bottom row, full length
    __shared__ float  s_red[4];
    __shared__ int    s_prog[4];         // last completed abs window per wave

    const int blk = blockIdx.x;
    const int b   = blk & 63;                  // batch (q*64+b: same-XCD bands)
    const int q   = blk >> 6;                  // band
    const int tid = threadIdx.x;
    const int l   = tid & 63;
    const int w_  = __builtin_amdgcn_readfirstlane(tid >> 6);
    const int g   = (q << 2) + w_;             // global wave 0..15
    const int gbase = g << 6;
    const int row   = gbase + l;

    if (tid < 4) s_prog[tid] = -1;

    const float* pr = pred   + ((size_t)b * TT + row) * 8;
    const float* tr = target + ((size_t)b * TT + row) * 8;
    const float4 pa = ((const float4*)pr)[0];
    const float4 pb = ((const float4*)pr)[1];
    const float4 ma = ((const float4*)tr)[0];
    const float4 mb = ((const float4*)tr)[1];

    float x2 = 0.f, msep = 0.f;
    {
        const float pp[8] = {pa.x,pa.y,pa.z,pa.w,pb.x,pb.y,pb.z,pb.w};
        const float tt[8] = {ma.x,ma.y,ma.z,ma.w,mb.x,mb.y,mb.z,mb.w};
        #pragma unroll
        for (int c = 0; c < 8; ++c) {
            x2 = fmaf(pp[c], pp[c], x2);
            float d = pp[c] - tt[c];
            msep = fmaf(d, d, msep);
        }
    }
    // stage all 1024 columns (4 per thread), swizzled layout
    const float* tg = target + (size_t)b * TT * 8;
    #pragma unroll
    for (int c0 = 0; c0 < 4; ++c0) {
        const int col = tid + (c0 << 8);
        const float4 u0 = ((const float4*)(tg + (size_t)col * 8))[0];
        const float4 u1 = ((const float4*)(tg + (size_t)col * 8))[1];
        const int ix = 2*col + ((col >> 2) & 7);
        s_c4[ix]   = make_float4(-2.f*u0.x, -2.f*u0.y, -2.f*u0.z, -2.f*u0.w);
        s_c4[ix+1] = make_float4(-2.f*u1.x, -2.f*u1.y, -2.f*u1.z, -2.f*u1.w);
        s_y2[col] = u0.x*u0.x + u0.y*u0.y + u0.z*u0.z + u0.w*u0.w
                  + u1.x*u1.x + u1.y*u1.y + u1.z*u1.z + u1.w*u1.w;
    }
    #pragma unroll
    for (int off = 32; off > 0; off >>= 1) msep += __shfl_down(msep, off, 64);
    if (l == 0) s_red[w_] = msep;
    __syncthreads();                      // the ONLY block-wide barrier
    if (tid == 0) ws[blk] = s_red[0] + s_red[1] + s_red[2] + s_red[3];

    unsigned long long* rings = (unsigned long long*)(ws + 320);
    unsigned long long* pub = rings + (size_t)(q * 64 + b) * RING;       // w_==3,q<3
    unsigned long long* con = rings + (size_t)((q - 1) * 64 + b) * RING; // w_==0,q>0
    const int kb_pub   = 256 * q + 192;
    const int kb_con   = 256 * q - 64;
    const int kmax_con = kb_con + 1086;

    const float c1 = 7.213475204444817f;     // log2(e)/gamma
    const float c2 = 0.13862943611198906f;   // gamma*ln(2)
    const int amin = g << 2;                 // first abs window = 4g
    const int amax = amin + 67;
    const int prodmax = amin + 63;           // producer wave's amax = 4(g-1)+67

    float r1 = FINF, r2 = FINF;
    unsigned long long pe1 = 0, pe2 = 0;
    int ppf = 0;
    float hpf1 = 0.f, hpf2 = 0.f;
    int hpff = 0;
    float hv, hvd;

    // stage halo hv (diag k0-1) / hvd (diag k0-2), row gbase-1
    auto stage_halo = [&](int a, int k0, int u) {
        if (w_ == 0) {
            if (q == 0) {
                hv  = FINF;
                hvd = (u == 0 && l == 0) ? 0.0f : FINF;
            } else {
                const int kk1 = k0 - 1 + l, kk2 = k0 - 2 + l;
                const int id1 = min(kk1 - kb_con, RING - 1);
                const int id2 = min(kk2 - kb_con, RING - 1);
                const bool n1 = (l < 16) && (kk1 <= kmax_con);
                const bool n2 = (l < 16) && (kk2 <= kmax_con);
                unsigned long long e1, e2;
                if (ppf) { e1 = pe1; e2 = pe2; ppf = 0; }
                else {
                    e1 = __hip_atomic_load(con + id1, __ATOMIC_RELAXED,
                                           __HIP_MEMORY_SCOPE_AGENT);
                    e2 = __hip_atomic_load(con + id2, __ATOMIC_RELAXED,
                                           __HIP_MEMORY_SCOPE_AGENT);
                }
                while (!__all(((!n1) | ((int)(e1 >> 32) == kk1)) &
                              ((!n2) | ((int)(e2 >> 32) == kk2)))) {
                    e1 = __hip_atomic_load(con + id1, __ATOMIC_RELAXED,
                                           __HIP_MEMORY_SCOPE_AGENT);
                    e2 = __hip_atomic_load(con + id2, __ATOMIC_RELAXED,
                                           __HIP_MEMORY_SCOPE_AGENT);
                }
                hv  = n1 ? __uint_as_float((unsigned)e1) : FINF;
                hvd = n2 ? __uint_as_float((unsigned)e2) : FINF;
            }
        } else {
            if (hpff) { hv = hpf1; hvd = hpf2; hpff = 0; }
            else {
                const int need = (a < prodmax) ? a : prodmax;
                int pv;
                do {
                    pv = __hip_atomic_load(&s_prog[w_ - 1], __ATOMIC_ACQUIRE,
                                           __HIP_MEMORY_SCOPE_WORKGROUP);
                } while (pv < need);
                const int bi = (u << 4) + 63 + l;     // k0-1+l in producer row
                hv  = s_row[w_ - 1][min(bi,     1087)];
                hvd = s_row[w_ - 1][min(bi - 1, 1087)];
            }
        }
    };

// ---- D: distance for one diag, per-lane swizzled LDS loads ----
// unclamped fast path (interior: j guaranteed in [1,1023])
#define DFAST(i, DST) do {                                                  \
        const int j_  = jb1 + (i);                                          \
        const int ix_ = 2*j_ + ((j_ >> 2) & 7);                             \
        const float4 va_ = s_c4[ix_];                                       \
        const float4 vb_ = s_c4[ix_+1];                                     \
        const float  yv_ = s_y2[j_];                                        \
        float ac_ = x2 + yv_, ac2_ = 0.f;                                   \
        ac_  = fmaf(pa.x, va_.x, ac_ );  ac2_ = fmaf(pa.y, va_.y, ac2_);    \
        ac_  = fmaf(pa.z, va_.z, ac_ );  ac2_ = fmaf(pa.w, va_.w, ac2_);    \
        ac_  = fmaf(pb.x, vb_.x, ac_ );  ac2_ = fmaf(pb.y, vb_.y, ac2_);    \
        ac_  = fmaf(pb.z, vb_.z, ac_ );  ac2_ = fmaf(pb.w, vb_.w, ac2_);    \
        DST = ac_ + ac2_;                                                   \
    } while (0)

// clamped path (edge windows)
#define DCLAMP(JB, i, DST) do {                                             \
        int jc_ = (JB) + (i);                                               \
        jc_ = jc_ < 0 ? 0 : (jc_ > (TT-1) ? (TT-1) : jc_);                  \
        const int ix_ = 2*jc_ + ((jc_ >> 2) & 7);                           \
        const float4 va_ = s_c4[ix_];                                       \
        const float4 vb_ = s_c4[ix_+1];                                     \
        const float  yv_ = s_y2[jc_];                                       \
        float ac_ = x2 + yv_, ac2_ = 0.f;                                   \
        ac_  = fmaf(pa.x, va_.x, ac_ );  ac2_ = fmaf(pa.y, va_.y, ac2_);    \
        ac_  = fmaf(pa.z, va_.z, ac_ );  ac2_ = fmaf(pa.w, va_.w, ac2_);    \
        ac_  = fmaf(pb.x, vb_.x, ac_ );  ac2_ = fmaf(pb.y, vb_.y, ac2_);    \
        ac_  = fmaf(pb.z, vb_.z, ac_ );  ac2_ = fmaf(pb.w, vb_.w, ac2_);    \
        DST = ac_ + ac2_;                                                   \
    } while (0)

// ---- R: one softmin recurrence step.  MASKED is a literal 0/1. ----
#define RSTEP(i, DIN, RH, MASKED) do {                                      \
        const float up_   = shflup1(hv,  r1);                               \
        const float dgv_  = shflup1(hvd, r2);                               \
        const float left_ = r1;                                             \
        hv = rotdn1(hv); hvd = rotdn1(hvd);                                 \
        float m_, M_;                                                       \
        asm("v_min3_f32 %0, %1, %2, %3"                                     \
            : "=v"(m_) : "v"(up_), "v"(left_), "v"(dgv_));                  \
        asm("v_max3_f32 %0, %1, %2, %3"                                     \
            : "=v"(M_) : "v"(up_), "v"(left_), "v"(dgv_));                  \
        const float md_ = __builtin_amdgcn_fmed3f(up_, left_, dgv_);        \
        const float mc_ = m_ * c1;                                          \
        const float ea_ = __builtin_amdgcn_exp2f(fmaf(md_, -c1, mc_));      \
        const float eb_ = __builtin_amdgcn_exp2f(fmaf(M_,  -c1, mc_));      \
        const float lg_ = __builtin_amdgcn_logf((1.0f + ea_) + eb_);        \
        float rn_ = (DIN) + fmaf(-c2, lg_, m_);                             \
        if (MASKED)                                                         \
            rn_ = ((unsigned)(jb0 + (i)) < (unsigned)TT) ? rn_ : FINF;      \
        r2 = r1; r1 = rn_; RH = rn_;                                        \
    } while (0)

    // D for window 0 (prologue, clamped)
    float Dc0,Dc1,Dc2,Dc3,Dc4,Dc5,Dc6,Dc7;
    float Dc8,Dc9,Dc10,Dc11,Dc12,Dc13,Dc14,Dc15;
    {
        const int jb = -l;
        DCLAMP(jb, 0,Dc0 ); DCLAMP(jb, 1,Dc1 ); DCLAMP(jb, 2,Dc2 );
        DCLAMP(jb, 3,Dc3 ); DCLAMP(jb, 4,Dc4 ); DCLAMP(jb, 5,Dc5 );
        DCLAMP(jb, 6,Dc6 ); DCLAMP(jb, 7,Dc7 ); DCLAMP(jb, 8,Dc8 );
        DCLAMP(jb, 9,Dc9 ); DCLAMP(jb,10,Dc10); DCLAMP(jb,11,Dc11);
        DCLAMP(jb,12,Dc12); DCLAMP(jb,13,Dc13); DCLAMP(jb,14,Dc14);
        DCLAMP(jb,15,Dc15);
    }
    float rh14_last = FINF;

    for (int u = 0; u <= 67; ++u) {
        const int a  = amin + u;
        const int k0 = a << 4;
        const int jb0 = (u << 4) - l;        // col index of diag k0 at this lane
        const int jb1 = jb0 + 16;            // same for window u+1

        stage_halo(a, k0, u);

        float E0,E1,E2,E3,E4,E5,E6,E7,E8,E9,E10,E11,E12,E13,E14,E15;
        float rh0,rh1,rh2,rh3,rh4,rh5,rh6,rh7;
        float rh8,rh9,rh10,rh11,rh12,rh13,rh14,rh15;

        if (u >= 4 && u <= 62) {
            // hot fused path: R(u) interleaved with D(u+1), both unguarded
            RSTEP( 0,Dc0 ,rh0 ,0); DFAST( 0,E0 );
            RSTEP( 1,Dc1 ,rh1 ,0); DFAST( 1,E1 );
            RSTEP( 2,Dc2 ,rh2 ,0); DFAST( 2,E2 );
            RSTEP( 3,Dc3 ,rh3 ,0); DFAST( 3,E3 );
            RSTEP( 4,Dc4 ,rh4 ,0); DFAST( 4,E4 );
            RSTEP( 5,Dc5 ,rh5 ,0); DFAST( 5,E5 );
            RSTEP( 6,Dc6 ,rh6 ,0); DFAST( 6,E6 );
            RSTEP( 7,Dc7 ,rh7 ,0); DFAST( 7,E7 );
            RSTEP( 8,Dc8 ,rh8 ,0); DFAST( 8,E8 );
            RSTEP( 9,Dc9 ,rh9 ,0); DFAST( 9,E9 );
            RSTEP(10,Dc10,rh10,0); DFAST(10,E10);
            RSTEP(11,Dc11,rh11,0); DFAST(11,E11);
            RSTEP(12,Dc12,rh12,0); DFAST(12,E12);
            RSTEP(13,Dc13,rh13,0); DFAST(13,E13);
            RSTEP(14,Dc14,rh14,0); DFAST(14,E14);
            RSTEP(15,Dc15,rh15,0); DFAST(15,E15);
        } else {
            // edge windows: masked R; clamped D for u+1 (skip at u=67)
            RSTEP( 0,Dc0 ,rh0 ,1); RSTEP( 1,Dc1 ,rh1 ,1);
            RSTEP( 2,Dc2 ,rh2 ,1); RSTEP( 3,Dc3 ,rh3 ,1);
            RSTEP( 4,Dc4 ,rh4 ,1); RSTEP( 5,Dc5 ,rh5 ,1);
            RSTEP( 6,Dc6 ,rh6 ,1); RSTEP( 7,Dc7 ,rh7 ,1);
            RSTEP( 8,Dc8 ,rh8 ,1); RSTEP( 9,Dc9 ,rh9 ,1);
            RSTEP(10,Dc10,rh10,1); RSTEP(11,Dc11,rh11,1);
            RSTEP(12,Dc12,rh12,1); RSTEP(13,Dc13,rh13,1);
            RSTEP(14,Dc14,rh14,1); RSTEP(15,Dc15,rh15,1);
            if (u < 67) {
                DCLAMP(jb1, 0,E0 ); DCLAMP(jb1, 1,E1 ); DCLAMP(jb1, 2,E2 );
                DCLAMP(jb1, 3,E3 ); DCLAMP(jb1, 4,E4 ); DCLAMP(jb1, 5,E5 );
                DCLAMP(jb1, 6,E6 ); DCLAMP(jb1, 7,E7 ); DCLAMP(jb1, 8,E8 );
                DCLAMP(jb1, 9,E9 ); DCLAMP(jb1,10,E10); DCLAMP(jb1,11,E11);
                DCLAMP(jb1,12,E12); DCLAMP(jb1,13,E13); DCLAMP(jb1,14,E14);
                DCLAMP(jb1,15,E15);
            } else {
                E0=E1=E2=E3=E4=E5=E6=E7=0.f;
                E8=E9=E10=E11=E12=E13=E14=E15=0.f;
                rh14_last = rh14;
            }
        }

        // bottom-row store (packed; masked FINF entries are correct values)
        if (l == 63) {
            float4* dst = (float4*)&s_row[w_][u << 4];
            dst[0] = make_float4(rh0,  rh1,  rh2,  rh3);
            dst[1] = make_float4(rh4,  rh5,  rh6,  rh7);
            dst[2] = make_float4(rh8,  rh9,  rh10, rh11);
            dst[3] = make_float4(rh12, rh13, rh14, rh15);
        }
        // rotate D buffers
        Dc0=E0;  Dc1=E1;  Dc2=E2;  Dc3=E3;  Dc4=E4;  Dc5=E5;  Dc6=E6;  Dc7=E7;
        Dc8=E8;  Dc9=E9;  Dc10=E10;Dc11=E11;Dc12=E12;Dc13=E13;Dc14=E14;Dc15=E15;

        // ---- mark window complete for intra-block consumer ----
        if (w_ < 3 && l == 0) {
            __hip_atomic_store(&s_prog[w_], a, __ATOMIC_RELEASE,
                               __HIP_MEMORY_SCOPE_WORKGROUP);
        }
        // ---- producer: publish window as self-validating u64 entries ----
        if (w_ == 3 && q < 3) {
            if (l < 16) {
                const int kk = k0 + l;
                const unsigned long long ev =
                    ((unsigned long long)(unsigned)kk << 32) |
                    (unsigned long long)__float_as_uint(s_row[3][(u << 4) + l]);
                __hip_atomic_store(pub + (kk - kb_pub), ev,
                                   __ATOMIC_RELAXED, __HIP_MEMORY_SCOPE_AGENT);
            }
        }
        // ---- cross-block consumer: prefetch next window's halo entries ----
        if (w_ == 0 && q > 0 && a < amax) {
            const int k0n = k0 + 16;
            const int kk1 = k0n - 1 + l, kk2 = k0n - 2 + l;
            pe1 = __hip_atomic_load(con + min(kk1 - kb_con, RING - 1),
                                    __ATOMIC_RELAXED, __HIP_MEMORY_SCOPE_AGENT);
            pe2 = __hip_atomic_load(con + min(kk2 - kb_con, RING - 1),
                                    __ATOMIC_RELAXED, __HIP_MEMORY_SCOPE_AGENT);
            ppf = 1;
        }
        // ---- intra-block consumer: prefetch next window's halo if ready ----
        if (w_ != 0 && a < amax) {
            const int neednx = ((a + 1) < prodmax) ? (a + 1) : prodmax;
            const int pv = __hip_atomic_load(&s_prog[w_ - 1], __ATOMIC_ACQUIRE,
                                             __HIP_MEMORY_SCOPE_WORKGROUP);
            if (pv >= neednx) {
                const int bi = ((u + 1) << 4) + 63 + l;
                hpf1 = s_row[w_ - 1][min(bi,     1087)];
                hpf2 = s_row[w_ - 1][min(bi - 1, 1087)];
                hpff = 1;
            }
        }
    }
    if (q == 3 && tid == 255) ws[256 + b] = rh14_last;   // r_{2T-2}(T-1)
#undef DFAST
#undef DCLAMP
#undef RSTEP
}

__global__ __launch_bounds__(256) void finalize2_kernel(
    const float* __restrict__ ws, float* __restrict__ out)
{
    __shared__ float sm[4], ss[4];
    const int tid = threadIdx.x, l = tid & 63, w = tid >> 6;
    float m  = ws[tid];
    float sd = (tid < 64) ? ws[256 + tid] : 0.f;
    #pragma unroll
    for (int off = 32; off > 0; off >>= 1) {
        m  += __shfl_down(m,  off, 64);
        sd += __shfl_down(sd, off, 64);
    }
    if (l == 0) { sm[w] = m; ss[w] = sd; }
    __syncthreads();
    if (tid == 0) {
        float M = sm[0] + sm[1] + sm[2] + sm[3];
        float S = ss[0] + ss[1] + ss[2] + ss[3];
        out[0] = ALPHA_ * (M / 524288.0f) + (1.0f - ALPHA_) * (S / 64.0f);
    }
}

extern "C" void kernel_launch(void* const* d_in, const int* in_sizes, int n_in,
                              void* d_out, int out_size, void* d_ws, size_t ws_size,
                              hipStream_t stream) {
    const float* pred   = (const float*)d_in[0];
    const float* target = (const float*)d_in[1];
    float* ws  = (float*)d_ws;
    float* out = (float*)d_out;

    sdtw_band_kernel<<<256, 256, 0, stream>>>(pred, target, ws);
    finalize2_kernel<<<1, 256, 0, stream>>>(ws, out);
}

// Round 8
// 314.156 us; speedup vs baseline: 1.0727x; 1.0727x over previous
//
#include <hip/hip_runtime.h>

// CombinedLoss: 0.7*MSE + 0.3*mean_b softDTW_gamma.  B=64, T=1024, C=8, fp32.
// R15 = R13 + PROVABLY-injective padded column layout (R14's swizzle had
// index collisions -> absmax 16 + MORE conflicts; reverted).
// Layout: column j occupies s_c4[3j] (A-half), s_c4[3j+1] (B-half),
// s_c4[3j+2].x (=y2[j], rest pad).  48B stride -> A start bank (12j)%32:
// any 8 consecutive lanes tile all 32 banks exactly once = LDS floor
// (R13's 32B stride used only banks {0,8,16,24}+3 -> 16-way, 8.5M conflicts).
// RSTEP bit-identical to R13.  Everything else unchanged: fused R(u)||D(u+1)
// windows, 256 blocks x 256 thr, 1 wave/SIMD, free-running waves, LDS
// progress flags intra-block, self-validating 8B atomics cross-block.
// ws: [0,256) mse | [256,320) sdtw | u64 rings @ float-offset 320 (~1.6 MB).

constexpr int TT = 1024;
constexpr float ALPHA_ = 0.7f;
constexpr float FINF = 1000000000.0f;
constexpr int RING = 1088;

__device__ __forceinline__ float shflup1(float old0, float v) {
    return __int_as_float(__builtin_amdgcn_update_dpp(
        __float_as_int(old0), __float_as_int(v), 0x138, 0xf, 0xf, false));
}
__device__ __forceinline__ float rotdn1(float v) {
    return __int_as_float(__builtin_amdgcn_update_dpp(
        0, __float_as_int(v), 0x130, 0xf, 0xf, false));
}

__global__ __launch_bounds__(256) void sdtw_band_kernel(
    const float* __restrict__ pred, const float* __restrict__ target,
    float* __restrict__ ws)
{
    // col j: A-half at 3j, B-half at 3j+1, y2 at 3j+2.x (48B stride)
    __shared__ float4 s_c4[TT * 3];
    __shared__ float  s_row[4][1088];    // per-wave bottom row, full length
    __shared__ float  s_red[4];
    __shared__ int    s_prog[4];         // last completed abs window per wave

    const int blk = blockIdx.x;
    const int b   = blk & 63;                  // batch (q*64+b: same-XCD bands)
    const int q   = blk >> 6;                  // band
    const int tid = threadIdx.x;
    const int l   = tid & 63;
    const int w_  = __builtin_amdgcn_readfirstlane(tid >> 6);
    const int g   = (q << 2) + w_;             // global wave 0..15
    const int gbase = g << 6;
    const int row   = gbase + l;

    if (tid < 4) s_prog[tid] = -1;

    const float* pr = pred   + ((size_t)b * TT + row) * 8;
    const float* tr = target + ((size_t)b * TT + row) * 8;
    const float4 pa = ((const float4*)pr)[0];
    const float4 pb = ((const float4*)pr)[1];
    const float4 ma = ((const float4*)tr)[0];
    const float4 mb = ((const float4*)tr)[1];

    float x2 = 0.f, msep = 0.f;
    {
        const float pp[8] = {pa.x,pa.y,pa.z,pa.w,pb.x,pb.y,pb.z,pb.w};
        const float tt[8] = {ma.x,ma.y,ma.z,ma.w,mb.x,mb.y,mb.z,mb.w};
        #pragma unroll
        for (int c = 0; c < 8; ++c) {
            x2 = fmaf(pp[c], pp[c], x2);
            float d = pp[c] - tt[c];
            msep = fmaf(d, d, msep);
        }
    }
    // stage all 1024 columns (4 per thread), padded layout
    const float* tg = target + (size_t)b * TT * 8;
    #pragma unroll
    for (int c0 = 0; c0 < 4; ++c0) {
        const int col = tid + (c0 << 8);
        const float4 u0 = ((const float4*)(tg + (size_t)col * 8))[0];
        const float4 u1 = ((const float4*)(tg + (size_t)col * 8))[1];
        const float y2 = u0.x*u0.x + u0.y*u0.y + u0.z*u0.z + u0.w*u0.w
                       + u1.x*u1.x + u1.y*u1.y + u1.z*u1.z + u1.w*u1.w;
        s_c4[3*col]   = make_float4(-2.f*u0.x, -2.f*u0.y, -2.f*u0.z, -2.f*u0.w);
        s_c4[3*col+1] = make_float4(-2.f*u1.x, -2.f*u1.y, -2.f*u1.z, -2.f*u1.w);
        s_c4[3*col+2] = make_float4(y2, 0.f, 0.f, 0.f);
    }
    #pragma unroll
    for (int off = 32; off > 0; off >>= 1) msep += __shfl_down(msep, off, 64);
    if (l == 0) s_red[w_] = msep;
    __syncthreads();                      // the ONLY block-wide barrier
    if (tid == 0) ws[blk] = s_red[0] + s_red[1] + s_red[2] + s_red[3];

    unsigned long long* rings = (unsigned long long*)(ws + 320);
    unsigned long long* pub = rings + (size_t)(q * 64 + b) * RING;       // w_==3,q<3
    unsigned long long* con = rings + (size_t)((q - 1) * 64 + b) * RING; // w_==0,q>0
    const int kb_pub   = 256 * q + 192;
    const int kb_con   = 256 * q - 64;
    const int kmax_con = kb_con + 1086;

    const float c1 = 7.213475204444817f;     // log2(e)/gamma
    const float c2 = 0.13862943611198906f;   // gamma*ln(2)
    const int amin = g << 2;                 // first abs window = 4g
    const int amax = amin + 67;
    const int prodmax = amin + 63;           // producer wave's amax = 4(g-1)+67

    float r1 = FINF, r2 = FINF;
    unsigned long long pe1 = 0, pe2 = 0;
    int ppf = 0;
    float hpf1 = 0.f, hpf2 = 0.f;
    int hpff = 0;
    float hv, hvd;

    // stage halo hv (diag k0-1) / hvd (diag k0-2), row gbase-1
    auto stage_halo = [&](int a, int k0, int u) {
        if (w_ == 0) {
            if (q == 0) {
                hv  = FINF;
                hvd = (u == 0 && l == 0) ? 0.0f : FINF;
            } else {
                const int kk1 = k0 - 1 + l, kk2 = k0 - 2 + l;
                const int id1 = min(kk1 - kb_con, RING - 1);
                const int id2 = min(kk2 - kb_con, RING - 1);
                const bool n1 = (l < 16) && (kk1 <= kmax_con);
                const bool n2 = (l < 16) && (kk2 <= kmax_con);
                unsigned long long e1, e2;
                if (ppf) { e1 = pe1; e2 = pe2; ppf = 0; }
                else {
                    e1 = __hip_atomic_load(con + id1, __ATOMIC_RELAXED,
                                           __HIP_MEMORY_SCOPE_AGENT);
                    e2 = __hip_atomic_load(con + id2, __ATOMIC_RELAXED,
                                           __HIP_MEMORY_SCOPE_AGENT);
                }
                while (!__all(((!n1) | ((int)(e1 >> 32) == kk1)) &
                              ((!n2) | ((int)(e2 >> 32) == kk2)))) {
                    e1 = __hip_atomic_load(con + id1, __ATOMIC_RELAXED,
                                           __HIP_MEMORY_SCOPE_AGENT);
                    e2 = __hip_atomic_load(con + id2, __ATOMIC_RELAXED,
                                           __HIP_MEMORY_SCOPE_AGENT);
                }
                hv  = n1 ? __uint_as_float((unsigned)e1) : FINF;
                hvd = n2 ? __uint_as_float((unsigned)e2) : FINF;
            }
        } else {
            if (hpff) { hv = hpf1; hvd = hpf2; hpff = 0; }
            else {
                const int need = (a < prodmax) ? a : prodmax;
                int pv;
                do {
                    pv = __hip_atomic_load(&s_prog[w_ - 1], __ATOMIC_ACQUIRE,
                                           __HIP_MEMORY_SCOPE_WORKGROUP);
                } while (pv < need);
                const int bi = (u << 4) + 63 + l;     // k0-1+l in producer row
                hv  = s_row[w_ - 1][min(bi,     1087)];
                hvd = s_row[w_ - 1][min(bi - 1, 1087)];
            }
        }
    };

// ---- D: distance for one diag, per-lane padded-layout LDS loads ----
// unclamped fast path (interior: j guaranteed in [1,1023])
#define DFAST(i, DST) do {                                                  \
        const int j_  = jb1 + (i);                                          \
        const float4 va_ = s_c4[3*j_];                                      \
        const float4 vb_ = s_c4[3*j_+1];                                    \
        const float  yv_ = s_c4[3*j_+2].x;                                  \
        float ac_ = x2 + yv_, ac2_ = 0.f;                                   \
        ac_  = fmaf(pa.x, va_.x, ac_ );  ac2_ = fmaf(pa.y, va_.y, ac2_);    \
        ac_  = fmaf(pa.z, va_.z, ac_ );  ac2_ = fmaf(pa.w, va_.w, ac2_);    \
        ac_  = fmaf(pb.x, vb_.x, ac_ );  ac2_ = fmaf(pb.y, vb_.y, ac2_);    \
        ac_  = fmaf(pb.z, vb_.z, ac_ );  ac2_ = fmaf(pb.w, vb_.w, ac2_);    \
        DST = ac_ + ac2_;                                                   \
    } while (0)

// clamped path (edge windows)
#define DCLAMP(JB, i, DST) do {                                             \
        int jc_ = (JB) + (i);                                               \
        jc_ = jc_ < 0 ? 0 : (jc_ > (TT-1) ? (TT-1) : jc_);                  \
        const float4 va_ = s_c4[3*jc_];                                     \
        const float4 vb_ = s_c4[3*jc_+1];                                   \
        const float  yv_ = s_c4[3*jc_+2].x;                                 \
        float ac_ = x2 + yv_, ac2_ = 0.f;                                   \
        ac_  = fmaf(pa.x, va_.x, ac_ );  ac2_ = fmaf(pa.y, va_.y, ac2_);    \
        ac_  = fmaf(pa.z, va_.z, ac_ );  ac2_ = fmaf(pa.w, va_.w, ac2_);    \
        ac_  = fmaf(pb.x, vb_.x, ac_ );  ac2_ = fmaf(pb.y, vb_.y, ac2_);    \
        ac_  = fmaf(pb.z, vb_.z, ac_ );  ac2_ = fmaf(pb.w, vb_.w, ac2_);    \
        DST = ac_ + ac2_;                                                   \
    } while (0)

// ---- R: one softmin recurrence step (bit-identical to R13). ----
#define RSTEP(i, DIN, RH, MASKED) do {                                      \
        const float up_   = shflup1(hv,  r1);                               \
        const float dgv_  = shflup1(hvd, r2);                               \
        const float left_ = r1;                                             \
        hv = rotdn1(hv); hvd = rotdn1(hvd);                                 \
        float m_, M_;                                                       \
        asm("v_min3_f32 %0, %1, %2, %3"                                     \
            : "=v"(m_) : "v"(up_), "v"(left_), "v"(dgv_));                  \
        asm("v_max3_f32 %0, %1, %2, %3"                                     \
            : "=v"(M_) : "v"(up_), "v"(left_), "v"(dgv_));                  \
        const float md_ = __builtin_amdgcn_fmed3f(up_, left_, dgv_);        \
        const float mc_ = m_ * c1;                                          \
        const float ea_ = __builtin_amdgcn_exp2f(fmaf(md_, -c1, mc_));      \
        const float eb_ = __builtin_amdgcn_exp2f(fmaf(M_,  -c1, mc_));      \
        const float lg_ = __builtin_amdgcn_logf(1.0f + (ea_ + eb_));        \
        float rn_ = (DIN) + fmaf(-c2, lg_, m_);                             \
        if (MASKED)                                                         \
            rn_ = ((unsigned)(jb0 + (i)) < (unsigned)TT) ? rn_ : FINF;      \
        r2 = r1; r1 = rn_; RH = rn_;                                        \
    } while (0)

    // D for window 0 (prologue, clamped)
    float Dc0,Dc1,Dc2,Dc3,Dc4,Dc5,Dc6,Dc7;
    float Dc8,Dc9,Dc10,Dc11,Dc12,Dc13,Dc14,Dc15;
    {
        const int jb = -l;
        DCLAMP(jb, 0,Dc0 ); DCLAMP(jb, 1,Dc1 ); DCLAMP(jb, 2,Dc2 );
        DCLAMP(jb, 3,Dc3 ); DCLAMP(jb, 4,Dc4 ); DCLAMP(jb, 5,Dc5 );
        DCLAMP(jb, 6,Dc6 ); DCLAMP(jb, 7,Dc7 ); DCLAMP(jb, 8,Dc8 );
        DCLAMP(jb, 9,Dc9 ); DCLAMP(jb,10,Dc10); DCLAMP(jb,11,Dc11);
        DCLAMP(jb,12,Dc12); DCLAMP(jb,13,Dc13); DCLAMP(jb,14,Dc14);
        DCLAMP(jb,15,Dc15);
    }
    float rh14_last = FINF;

    for (int u = 0; u <= 67; ++u) {
        const int a  = amin + u;
        const int k0 = a << 4;
        const int jb0 = (u << 4) - l;        // col index of diag k0 at this lane
        const int jb1 = jb0 + 16;            // same for window u+1

        stage_halo(a, k0, u);

        float E0,E1,E2,E3,E4,E5,E6,E7,E8,E9,E10,E11,E12,E13,E14,E15;
        float rh0,rh1,rh2,rh3,rh4,rh5,rh6,rh7;
        float rh8,rh9,rh10,rh11,rh12,rh13,rh14,rh15;

        if (u >= 4 && u <= 62) {
            // hot fused path: R(u) interleaved with D(u+1), both unguarded
            RSTEP( 0,Dc0 ,rh0 ,0); DFAST( 0,E0 );
            RSTEP( 1,Dc1 ,rh1 ,0); DFAST( 1,E1 );
            RSTEP( 2,Dc2 ,rh2 ,0); DFAST( 2,E2 );
            RSTEP( 3,Dc3 ,rh3 ,0); DFAST( 3,E3 );
            RSTEP( 4,Dc4 ,rh4 ,0); DFAST( 4,E4 );
            RSTEP( 5,Dc5 ,rh5 ,0); DFAST( 5,E5 );
            RSTEP( 6,Dc6 ,rh6 ,0); DFAST( 6,E6 );
            RSTEP( 7,Dc7 ,rh7 ,0); DFAST( 7,E7 );
            RSTEP( 8,Dc8 ,rh8 ,0); DFAST( 8,E8 );
            RSTEP( 9,Dc9 ,rh9 ,0); DFAST( 9,E9 );
            RSTEP(10,Dc10,rh10,0); DFAST(10,E10);
            RSTEP(11,Dc11,rh11,0); DFAST(11,E11);
            RSTEP(12,Dc12,rh12,0); DFAST(12,E12);
            RSTEP(13,Dc13,rh13,0); DFAST(13,E13);
            RSTEP(14,Dc14,rh14,0); DFAST(14,E14);
            RSTEP(15,Dc15,rh15,0); DFAST(15,E15);
        } else {
            // edge windows: masked R; clamped D for u+1 (skip at u=67)
            RSTEP( 0,Dc0 ,rh0 ,1); RSTEP( 1,Dc1 ,rh1 ,1);
            RSTEP( 2,Dc2 ,rh2 ,1); RSTEP( 3,Dc3 ,rh3 ,1);
            RSTEP( 4,Dc4 ,rh4 ,1); RSTEP( 5,Dc5 ,rh5 ,1);
            RSTEP( 6,Dc6 ,rh6 ,1); RSTEP( 7,Dc7 ,rh7 ,1);
            RSTEP( 8,Dc8 ,rh8 ,1); RSTEP( 9,Dc9 ,rh9 ,1);
            RSTEP(10,Dc10,rh10,1); RSTEP(11,Dc11,rh11,1);
            RSTEP(12,Dc12,rh12,1); RSTEP(13,Dc13,rh13,1);
            RSTEP(14,Dc14,rh14,1); RSTEP(15,Dc15,rh15,1);
            if (u < 67) {
                DCLAMP(jb1, 0,E0 ); DCLAMP(jb1, 1,E1 ); DCLAMP(jb1, 2,E2 );
                DCLAMP(jb1, 3,E3 ); DCLAMP(jb1, 4,E4 ); DCLAMP(jb1, 5,E5 );
                DCLAMP(jb1, 6,E6 ); DCLAMP(jb1, 7,E7 ); DCLAMP(jb1, 8,E8 );
                DCLAMP(jb1, 9,E9 ); DCLAMP(jb1,10,E10); DCLAMP(jb1,11,E11);
                DCLAMP(jb1,12,E12); DCLAMP(jb1,13,E13); DCLAMP(jb1,14,E14);
                DCLAMP(jb1,15,E15);
            } else {
                E0=E1=E2=E3=E4=E5=E6=E7=0.f;
                E8=E9=E10=E11=E12=E13=E14=E15=0.f;
                rh14_last = rh14;
            }
        }

        // bottom-row store (packed; masked FINF entries are correct values)
        if (l == 63) {
            float4* dst = (float4*)&s_row[w_][u << 4];
            dst[0] = make_float4(rh0,  rh1,  rh2,  rh3);
            dst[1] = make_float4(rh4,  rh5,  rh6,  rh7);
            dst[2] = make_float4(rh8,  rh9,  rh10, rh11);
            dst[3] = make_float4(rh12, rh13, rh14, rh15);
        }
        // rotate D buffers
        Dc0=E0;  Dc1=E1;  Dc2=E2;  Dc3=E3;  Dc4=E4;  Dc5=E5;  Dc6=E6;  Dc7=E7;
        Dc8=E8;  Dc9=E9;  Dc10=E10;Dc11=E11;Dc12=E12;Dc13=E13;Dc14=E14;Dc15=E15;

        // ---- mark window complete for intra-block consumer ----
        if (w_ < 3 && l == 0) {
            __hip_atomic_store(&s_prog[w_], a, __ATOMIC_RELEASE,
                               __HIP_MEMORY_SCOPE_WORKGROUP);
        }
        // ---- producer: publish window as self-validating u64 entries ----
        if (w_ == 3 && q < 3) {
            if (l < 16) {
                const int kk = k0 + l;
                const unsigned long long ev =
                    ((unsigned long long)(unsigned)kk << 32) |
                    (unsigned long long)__float_as_uint(s_row[3][(u << 4) + l]);
                __hip_atomic_store(pub + (kk - kb_pub), ev,
                                   __ATOMIC_RELAXED, __HIP_MEMORY_SCOPE_AGENT);
            }
        }
        // ---- cross-block consumer: prefetch next window's halo entries ----
        if (w_ == 0 && q > 0 && a < amax) {
            const int k0n = k0 + 16;
            const int kk1 = k0n - 1 + l, kk2 = k0n - 2 + l;
            pe1 = __hip_atomic_load(con + min(kk1 - kb_con, RING - 1),
                                    __ATOMIC_RELAXED, __HIP_MEMORY_SCOPE_AGENT);
            pe2 = __hip_atomic_load(con + min(kk2 - kb_con, RING - 1),
                                    __ATOMIC_RELAXED, __HIP_MEMORY_SCOPE_AGENT);
            ppf = 1;
        }
        // ---- intra-block consumer: prefetch next window's halo if ready ----
        if (w_ != 0 && a < amax) {
            const int neednx = ((a + 1) < prodmax) ? (a + 1) : prodmax;
            const int pv = __hip_atomic_load(&s_prog[w_ - 1], __ATOMIC_ACQUIRE,
                                             __HIP_MEMORY_SCOPE_WORKGROUP);
            if (pv >= neednx) {
                const int bi = ((u + 1) << 4) + 63 + l;
                hpf1 = s_row[w_ - 1][min(bi,     1087)];
                hpf2 = s_row[w_ - 1][min(bi - 1, 1087)];
                hpff = 1;
            }
        }
    }
    if (q == 3 && tid == 255) ws[256 + b] = rh14_last;   // r_{2T-2}(T-1)
#undef DFAST
#undef DCLAMP
#undef RSTEP
}

__global__ __launch_bounds__(256) void finalize2_kernel(
    const float* __restrict__ ws, float* __restrict__ out)
{
    __shared__ float sm[4], ss[4];
    const int tid = threadIdx.x, l = tid & 63, w = tid >> 6;
    float m  = ws[tid];
    float sd = (tid < 64) ? ws[256 + tid] : 0.f;
    #pragma unroll
    for (int off = 32; off > 0; off >>= 1) {
        m  += __shfl_down(m,  off, 64);
        sd += __shfl_down(sd, off, 64);
    }
    if (l == 0) { sm[w] = m; ss[w] = sd; }
    __syncthreads();
    if (tid == 0) {
        float M = sm[0] + sm[1] + sm[2] + sm[3];
        float S = ss[0] + ss[1] + ss[2] + ss[3];
        out[0] = ALPHA_ * (M / 524288.0f) + (1.0f - ALPHA_) * (S / 64.0f);
    }
}

extern "C" void kernel_launch(void* const* d_in, const int* in_sizes, int n_in,
                              void* d_out, int out_size, void* d_ws, size_t ws_size,
                              hipStream_t stream) {
    const float* pred   = (const float*)d_in[0];
    const float* target = (const float*)d_in[1];
    float* ws  = (float*)d_ws;
    float* out = (float*)d_out;

    sdtw_band_kernel<<<256, 256, 0, stream>>>(pred, target, ws);
    finalize2_kernel<<<1, 256, 0, stream>>>(ws, out);
}